// Round 10
// baseline (260.097 us; speedup 1.0000x reference)
//
#include <hip/hip_runtime.h>
#include <hip/hip_bf16.h>
#include <cstdint>

#define NN 100000
#define NE 1600000
#define BSHIFT 9
#define BSIZE 512
#define NBKT ((NN + BSIZE - 1) / BSIZE)   // 196
#define BATCH 4096
#define NBATCH ((NE + BATCH - 1) / BATCH) // 391

using bf16x8 = __attribute__((ext_vector_type(8))) short;
using f32x4  = __attribute__((ext_vector_type(4))) float;

union BF8 { bf16x8 v; unsigned u[4]; };

__device__ __forceinline__ unsigned pk2(float lo, float hi) {
    union { __hip_bfloat162 b; unsigned u; } c;
    c.b = __float22bfloat162_rn(make_float2(lo, hi));
    return c.u;
}

// ---- phase A: bucket histogram (bucket = dst >> 9) ----
__global__ __launch_bounds__(256) void hist_kernel(
    const int* __restrict__ eidx, unsigned* __restrict__ hist)
{
    __shared__ unsigned h[NBKT];
    for (int i = threadIdx.x; i < NBKT; i += 256) h[i] = 0;
    __syncthreads();
    int stride = gridDim.x * 256;
    for (int e = blockIdx.x * 256 + threadIdx.x; e < NE; e += stride)
        atomicAdd(&h[((unsigned)eidx[NE + e]) >> BSHIFT], 1u);
    __syncthreads();
    for (int i = threadIdx.x; i < NBKT; i += 256)
        if (h[i]) atomicAdd(&hist[i], h[i]);
}

// ---- phase B: exclusive scan -> base + cursor ----
__global__ __launch_bounds__(256) void scan_kernel(
    const unsigned* __restrict__ hist, unsigned* __restrict__ base,
    unsigned* __restrict__ cursor)
{
    __shared__ unsigned s[256];
    int tid = threadIdx.x;
    unsigned v = (tid < NBKT) ? hist[tid] : 0;
    s[tid] = v;
    __syncthreads();
    for (int off = 1; off < 256; off <<= 1) {
        unsigned t = (tid >= off) ? s[tid - off] : 0;
        __syncthreads();
        s[tid] += t;
        __syncthreads();
    }
    unsigned excl = s[tid] - v;
    if (tid < NBKT) { base[tid] = excl; cursor[tid] = excl; }
    if (tid == 0) base[NBKT] = NE;
}

// ---- phase C: bin edges into bucket-contiguous records ----
// record: e[0:21) | src[21:38) | dl[38:47);  staging adds b in [56:64)
__global__ __launch_bounds__(256) void bin_kernel(
    const int* __restrict__ eidx, unsigned* __restrict__ cursor,
    unsigned long long* __restrict__ pairs)
{
    __shared__ unsigned long long stg[BATCH];
    __shared__ unsigned cnt[256];
    __shared__ unsigned slots[256];
    __shared__ unsigned sbase[256];
    __shared__ unsigned gbase[256];
    int tid = threadIdx.x;
    for (int bt = blockIdx.x; bt < NBATCH; bt += gridDim.x) {
        int b0 = bt * BATCH;
        int bcnt = min(BATCH, NE - b0);
        cnt[tid] = 0;
        __syncthreads();
        unsigned long long rec[16];
        unsigned br[16];
        #pragma unroll
        for (int k = 0; k < 16; ++k) {
            int E = b0 + k * 256 + tid;
            if (E < NE) {
                unsigned src = (unsigned)eidx[E];
                unsigned dst = (unsigned)eidx[NE + E];
                unsigned b = dst >> BSHIFT;
                unsigned r = atomicAdd(&cnt[b], 1u);
                rec[k] = (unsigned long long)(unsigned)E
                       | ((unsigned long long)src << 21)
                       | ((unsigned long long)(dst & (BSIZE - 1u)) << 38)
                       | ((unsigned long long)b << 56);
                br[k] = (b << 16) | r;
            } else br[k] = 0xFFFFFFFFu;
        }
        __syncthreads();
        slots[tid] = cnt[tid];
        __syncthreads();
        unsigned orig = slots[tid];
        for (int off = 1; off < 256; off <<= 1) {
            unsigned t = (tid >= off) ? slots[tid - off] : 0;
            __syncthreads();
            slots[tid] += t;
            __syncthreads();
        }
        sbase[tid] = slots[tid] - orig;
        __syncthreads();
        #pragma unroll
        for (int k = 0; k < 16; ++k) {
            if (br[k] != 0xFFFFFFFFu) {
                unsigned b = br[k] >> 16, r = br[k] & 0xFFFFu;
                stg[sbase[b] + r] = rec[k];
            }
        }
        if (tid < NBKT && cnt[tid])
            gbase[tid] = atomicAdd(&cursor[tid], cnt[tid]);
        __syncthreads();
        for (int i = tid; i < bcnt; i += 256) {
            unsigned long long r = stg[i];
            unsigned b = (unsigned)(r >> 56);
            pairs[gbase[b] + (i - sbase[b])] = r & 0x00FFFFFFFFFFFFFFULL;
        }
        __syncthreads();
    }
}

// ---- phase D: per-bucket aggregation, MFMA edge compute, LDS f32 acc,
// fused root transform, plain coalesced stores (zero global atomics) ----
__global__ __launch_bounds__(1024) void agg_kernel(
    const float* __restrict__ edge_attr,
    const unsigned long long* __restrict__ pairs,
    const unsigned* __restrict__ base, const float* __restrict__ x,
    const float* __restrict__ edge_w, const float* __restrict__ edge_b,
    const float* __restrict__ root_w, const float* __restrict__ root_b,
    float* __restrict__ out)
{
    __shared__ float acc[BSIZE * 16];   // 32 KB
    const int b = blockIdx.x;
    for (int i = threadIdx.x; i < BSIZE * 16; i += 1024) acc[i] = 0.f;

    const int lane = threadIdx.x & 63;
    const int row  = lane & 15;
    const int quad = lane >> 4;
    const int hi   = quad & 1;
    const int q2   = quad >> 1;

    BF8 bfrag[5];
    #pragma unroll
    for (int ks = 0; ks < 4; ++ks) {
        int d = ks * 2 + q2;
        const float4* p = (const float4*)(edge_w + d*256 + row*16 + hi*8);
        float4 w0 = p[0], w1 = p[1];
        bfrag[ks].u[0] = pk2(w0.x, w0.y);
        bfrag[ks].u[1] = pk2(w0.z, w0.w);
        bfrag[ks].u[2] = pk2(w1.x, w1.y);
        bfrag[ks].u[3] = pk2(w1.z, w1.w);
    }
    if (quad < 2) {
        const float4* p = (const float4*)(edge_b + row*16 + hi*8);
        float4 w0 = p[0], w1 = p[1];
        bfrag[4].u[0] = pk2(w0.x, w0.y);
        bfrag[4].u[1] = pk2(w0.z, w0.w);
        bfrag[4].u[2] = pk2(w1.x, w1.y);
        bfrag[4].u[3] = pk2(w1.z, w1.w);
    } else {
        bfrag[4].u[0] = bfrag[4].u[1] = bfrag[4].u[2] = bfrag[4].u[3] = 0;
    }
    __syncthreads();

    const unsigned rbeg = base[b];
    const int cnt = (int)(base[b + 1] - rbeg);
    const int T = (cnt + 15) >> 4;
    const int w = threadIdx.x >> 6;   // wave 0..15
    const int sxa = hi * 32 + row;
    const int sxb = sxa + 16;

    int t = w;
    if (t < T) {
        // stage 0
        int rem0 = min(16, cnt - t * 16);
        unsigned long long R0 = pairs[rbeg + t * 16 + min(row, rem0 - 1)];
        unsigned e0  = (unsigned)(R0 & 0x1FFFFFu);
        unsigned sc0 = (unsigned)(R0 >> 21) & 0x1FFFFu;
        float4 V0 = *(const float4*)(x + (size_t)sc0 * 16 + quad * 4);
        float2 E0 = *(const float2*)(edge_attr + (size_t)e0 * 8 + quad * 2);
        int t1 = t + 16;
        int tc1 = (t1 < T) ? t1 : (T - 1);
        int rem1 = min(16, cnt - tc1 * 16);
        unsigned long long R1 = pairs[rbeg + tc1 * 16 + min(row, rem1 - 1)];

        for (;;) {
            // prefetch stage-2 record + stage-1 payload
            int t2 = t1 + 16;
            int tc2 = (t2 < T) ? t2 : (T - 1);
            int rem2 = min(16, cnt - tc2 * 16);
            unsigned long long R2 = pairs[rbeg + tc2 * 16 + min(row, rem2 - 1)];
            unsigned e1  = (unsigned)(R1 & 0x1FFFFFu);
            unsigned sc1 = (unsigned)(R1 >> 21) & 0x1FFFFu;
            float4 V1 = *(const float4*)(x + (size_t)sc1 * 16 + quad * 4);
            float2 E1 = *(const float2*)(edge_attr + (size_t)e1 * 8 + quad * 2);

            // redistribute stage 0
            float4 xa0, xb0;
            xa0.x = __shfl(V0.x, sxa, 64);
            xa0.y = __shfl(V0.y, sxa, 64);
            xa0.z = __shfl(V0.z, sxa, 64);
            xa0.w = __shfl(V0.w, sxa, 64);
            xb0.x = __shfl(V0.x, sxb, 64);
            xb0.y = __shfl(V0.y, sxb, 64);
            xb0.z = __shfl(V0.z, sxb, 64);
            xb0.w = __shfl(V0.w, sxb, 64);
            float ex0 = __shfl(E0.x, row,      64);
            float ey0 = __shfl(E0.y, row,      64);
            float ex1 = __shfl(E0.x, row + 16, 64);
            float ey1 = __shfl(E0.y, row + 16, 64);
            float ex2 = __shfl(E0.x, row + 32, 64);
            float ey2 = __shfl(E0.y, row + 32, 64);
            float ex3 = __shfl(E0.x, row + 48, 64);
            float ey3 = __shfl(E0.y, row + 48, 64);
            float ad0 = q2 ? ey0 : ex0;
            float ad1 = q2 ? ey1 : ex1;
            float ad2 = q2 ? ey2 : ex2;
            float ad3 = q2 ? ey3 : ex3;

            f32x4 a = {0.f, 0.f, 0.f, 0.f};
            BF8 af;
            af.u[0] = pk2(ad0*xa0.x, ad0*xa0.y);
            af.u[1] = pk2(ad0*xa0.z, ad0*xa0.w);
            af.u[2] = pk2(ad0*xb0.x, ad0*xb0.y);
            af.u[3] = pk2(ad0*xb0.z, ad0*xb0.w);
            a = __builtin_amdgcn_mfma_f32_16x16x32_bf16(af.v, bfrag[0].v, a, 0, 0, 0);
            af.u[0] = pk2(ad1*xa0.x, ad1*xa0.y);
            af.u[1] = pk2(ad1*xa0.z, ad1*xa0.w);
            af.u[2] = pk2(ad1*xb0.x, ad1*xb0.y);
            af.u[3] = pk2(ad1*xb0.z, ad1*xb0.w);
            a = __builtin_amdgcn_mfma_f32_16x16x32_bf16(af.v, bfrag[1].v, a, 0, 0, 0);
            af.u[0] = pk2(ad2*xa0.x, ad2*xa0.y);
            af.u[1] = pk2(ad2*xa0.z, ad2*xa0.w);
            af.u[2] = pk2(ad2*xb0.x, ad2*xb0.y);
            af.u[3] = pk2(ad2*xb0.z, ad2*xb0.w);
            a = __builtin_amdgcn_mfma_f32_16x16x32_bf16(af.v, bfrag[2].v, a, 0, 0, 0);
            af.u[0] = pk2(ad3*xa0.x, ad3*xa0.y);
            af.u[1] = pk2(ad3*xa0.z, ad3*xa0.w);
            af.u[2] = pk2(ad3*xb0.x, ad3*xb0.y);
            af.u[3] = pk2(ad3*xb0.z, ad3*xb0.w);
            a = __builtin_amdgcn_mfma_f32_16x16x32_bf16(af.v, bfrag[3].v, a, 0, 0, 0);
            if (quad < 2) {
                af.u[0] = pk2(xa0.x, xa0.y);
                af.u[1] = pk2(xa0.z, xa0.w);
                af.u[2] = pk2(xb0.x, xb0.y);
                af.u[3] = pk2(xb0.z, xb0.w);
            } else {
                af.u[0] = af.u[1] = af.u[2] = af.u[3] = 0;
            }
            a = __builtin_amdgcn_mfma_f32_16x16x32_bf16(af.v, bfrag[4].v, a, 0, 0, 0);

            // LDS accumulate (masked for the partial tail tile)
            unsigned dl = (unsigned)(R0 >> 38) & 0x1FFu;
            int rem = min(16, cnt - t * 16);
            #pragma unroll
            for (int r = 0; r < 4; ++r) {
                int ei = quad * 4 + r;
                unsigned dlr = (unsigned)__shfl((int)dl, quad * 4 + r, 16);
                if (ei < rem) atomicAdd(&acc[dlr * 16 + row], a[r]);
            }

            if (t1 >= T) break;
            t = t1; t1 = t2; tc1 = tc2;
            R0 = R1; R1 = R2;
            V0 = V1; E0 = E1;
        }
    }
    __syncthreads();

    // fused root + flush: thread i handles node b*512 + i (i < 512)
    if (threadIdx.x < BSIZE) {
        int n = b * BSIZE + threadIdx.x;
        if (n < NN) {
            const float4* xp = (const float4*)(x + (size_t)n * 16);
            float4 x0 = xp[0], x1 = xp[1], x2 = xp[2], x3 = xp[3];
            float xv[16] = {x0.x,x0.y,x0.z,x0.w, x1.x,x1.y,x1.z,x1.w,
                            x2.x,x2.y,x2.z,x2.w, x3.x,x3.y,x3.z,x3.w};
            const float* ac = &acc[threadIdx.x * 16];
            float r[16];
            #pragma unroll
            for (int o = 0; o < 16; ++o) {
                float s = root_b[o] + ac[o];
                #pragma unroll
                for (int i = 0; i < 16; ++i) s += xv[i] * root_w[i*16 + o];
                r[o] = s;
            }
            float4* op = (float4*)(out + (size_t)n * 16);
            op[0] = make_float4(r[0], r[1], r[2], r[3]);
            op[1] = make_float4(r[4], r[5], r[6], r[7]);
            op[2] = make_float4(r[8], r[9], r[10], r[11]);
            op[3] = make_float4(r[12], r[13], r[14], r[15]);
        }
    }
}

extern "C" void kernel_launch(void* const* d_in, const int* in_sizes, int n_in,
                              void* d_out, int out_size, void* d_ws, size_t ws_size,
                              hipStream_t stream) {
    const float* x         = (const float*)d_in[0];
    const float* edge_attr = (const float*)d_in[1];
    const float* root_w    = (const float*)d_in[2];
    const float* root_b    = (const float*)d_in[3];
    const float* edge_w    = (const float*)d_in[4];
    const float* edge_b    = (const float*)d_in[5];
    const int*   eidx      = (const int*)d_in[6];
    float* out = (float*)d_out;

    // ws: hist[256] | base[257 pad 256] | cursor[256] | pairs[NE] u64
    unsigned* w32 = (unsigned*)d_ws;
    unsigned* hist   = w32;
    unsigned* basep  = w32 + 256;
    unsigned* cursor = w32 + 512;
    unsigned long long* pairs = (unsigned long long*)(w32 + 768);

    (void)hipMemsetAsync(hist, 0, 256 * 4, stream);
    hist_kernel<<<1024, 256, 0, stream>>>(eidx, hist);
    scan_kernel<<<1, 256, 0, stream>>>(hist, basep, cursor);
    bin_kernel<<<NBATCH, 256, 0, stream>>>(eidx, cursor, pairs);
    agg_kernel<<<NBKT, 1024, 0, stream>>>(edge_attr, pairs, basep, x,
                                          edge_w, edge_b, root_w, root_b, out);
}